// Round 11
// baseline (83.472 us; speedup 1.0000x reference)
//
#include <hip/hip_runtime.h>

// SpikingReadoutLayer (two-kernel; R10 structure at 8 blocks/CU):
//   h2[b,t,o] = sum_h in[b,t,h] * W[h,o]
//   flt' = a*flt + h_t ; out' = b*out + flt (OLD flt); out_rec[b,0,:]=0
//
// Kernel 1: one block per (b, t-chunk of 125 rows) -> 2048 blocks, 16.4 KB
// LDS, VGPR<=64 -> 8 blocks/CU = 32 waves/CU (max occupancy). Stage via
// __builtin_amdgcn_global_load_lds (16B DMA, no VGPR round-trip) into
// double-buffered LINEAR LDS (2 x 8 KB). Issue chunk c+1 -> compute chunk c
// -> __syncthreads (drains vmcnt) -> swap. Bank spread via XOR-swizzled
// GLOBAL source quad (q^(r&3)) + same XOR on read (both-sides rule).
// Thread-per-row compute; W read wave-uniform. Block-local scan in LDS
// (PAD=20, conflict-free), chunk-final states -> ws.
// Kernel 2: closed-form affine fixup (A^k analytic), float4 RMW (verified).

constexpr int B_ = 128, T_ = 2000, H_ = 256, O_ = 16;
constexpr int TOUT = T_ + 1;                 // 2001
constexpr int TC = 16, CL = 125;             // t-chunks per batch
constexpr int NHC = 16, HC = 16;             // h-chunks of 16 (64 B/row)
constexpr int BUFSLOTS = 512;                // 16B slots per buffer (>= CL*4, x256)
constexpr int PAD = 20;                      // scan tile row stride (floats)
constexpr float ALPHA = 0.95f, BETA = 0.9f;
constexpr float INV_AB = 20.0f;              // 1/(ALPHA-BETA)
constexpr float L2A = -0.07400058144377693f; // log2(0.95)
constexpr float L2B = -0.15200309344504997f; // log2(0.90)

#define AS1 __attribute__((address_space(1)))
#define AS3 __attribute__((address_space(3)))

__device__ __forceinline__ void gload16(const float* g, float* l) {
    __builtin_amdgcn_global_load_lds((const AS1 void*)g, (AS3 void*)l, 16, 0, 0);
}

// Stage one [CL x 16] h-chunk: slot f=(r,q) <- global quad (q ^ (r&3)) of
// row r. LDS dest linear (wave-uniform base + lane*16); swizzle lives in the
// global source (per-row 64B address set unchanged -> coalesced). Tail slots
// (f >= 500) clamp r to CL-1: they land in slots 500..511, never read.
__device__ __forceinline__ void stage_chunk(const float* __restrict__ inb, int c,
                                            float* dst, int tid) {
#pragma unroll
    for (int it = 0; it < 2; ++it) {
        const int f = it * 256 + tid;
        int r = f >> 2;
        if (r > CL - 1) r = CL - 1;
        const int q = f & 3;
        const float* g = inb + (size_t)r * H_ + c * HC + 4 * (q ^ (r & 3));
        gload16(g, dst + (size_t)f * 4);
    }
}

__global__ __launch_bounds__(256, 8)
void h2scan_kernel(const float* __restrict__ in, const float* __restrict__ W,
                   float* __restrict__ out, float* __restrict__ ws) {
    __shared__ float lds[2 * BUFSLOTS * 4 + 128];  // 16.5 KB: two stage buffers
    const int tid = threadIdx.x;
    const int b = blockIdx.x >> 4;            // TC = 16
    const int j = blockIdx.x & 15;

    const float* inb = in + ((size_t)b * T_ + (size_t)j * CL) * H_;
    const int row = (tid < CL) ? tid : 0;     // clamp for idle tail threads
    const int rsw = row & 3;

    float acc[16];
#pragma unroll
    for (int o = 0; o < 16; ++o) acc[o] = 0.f;

    stage_chunk(inb, 0, &lds[0], tid);
    __syncthreads();                          // drain chunk-0 DMA

    for (int c = 0; c < NHC; ++c) {
        float* cur = &lds[(c & 1) * (BUFSLOTS * 4)];
        if (c + 1 < NHC)                      // issue next chunk; flies during compute
            stage_chunk(inb, c + 1, &lds[((c + 1) & 1) * (BUFSLOTS * 4)], tid);

        // ---- compute: thread-per-row, 16 h x 16 o FMAs from swizzled LDS ----
        const float* __restrict__ Wc = W + c * HC * O_;  // wave-uniform reads
#pragma unroll
        for (int p = 0; p < 4; ++p) {
            const float4 v = *(const float4*)&cur[row * 16 + 4 * (p ^ rsw)];
            const float xv[4] = {v.x, v.y, v.z, v.w};
#pragma unroll
            for (int e = 0; e < 4; ++e) {
                const float x = xv[e];
                const float* wrow = Wc + (4 * p + e) * 16;
#pragma unroll
                for (int o = 0; o < 16; ++o)
                    acc[o] = fmaf(x, wrow[o], acc[o]);
            }
        }
        __syncthreads();   // drains next-chunk DMA; guards buffer reuse
    }

    // ---- acc -> scan tile (overlays buffers; post-barrier, safe) ----
    if (tid < CL) {
        float4* tp = (float4*)&lds[tid * PAD];
        tp[0] = make_float4(acc[0],  acc[1],  acc[2],  acc[3]);
        tp[1] = make_float4(acc[4],  acc[5],  acc[6],  acc[7]);
        tp[2] = make_float4(acc[8],  acc[9],  acc[10], acc[11]);
        tp[3] = make_float4(acc[12], acc[13], acc[14], acc[15]);
    }
    __syncthreads();

    // ---- 16 serial chains down the columns (conflict-free, PAD=20) ----
    if (tid < O_) {
        float flt = 0.f, oo = 0.f;
        float* col = &lds[tid];
#pragma unroll 5
        for (int t = 0; t < CL; ++t) {
            const float h = col[t * PAD];
            const float no = fmaf(BETA, oo, flt);  // uses OLD flt
            flt = fmaf(ALPHA, flt, h);
            col[t * PAD] = no;
            oo = no;
        }
        float* wp = ws + ((size_t)(b * O_ + tid) * TC + j) * 2;
        wp[0] = flt;
        wp[1] = oo;
        if (j == 0) out[(size_t)b * TOUT * O_ + tid] = 0.f;  // out_rec[b,0,o]
    }
    __syncthreads();

    // ---- coalesced float4 writeback of LOCAL outputs ----
    float4* ob = (float4*)(out + ((size_t)b * TOUT + (size_t)j * CL + 1) * O_);
#pragma unroll
    for (int it = 0; it < 2; ++it) {              // CL*O_/4 = 500 float4
        const int e4 = it * 256 + tid;
        if (e4 < CL * 4) {
            const int tloc = e4 >> 2, qo = 4 * (e4 & 3);
            const float* tp = &lds[tloc * PAD + qo];
            ob[e4] = make_float4(tp[0], tp[1], tp[2], tp[3]);
        }
    }
}

// Kernel 2: chunk j>0 start state s0 = sum_{m<j} A^{CL*(j-1-m)} * sigma_m,
// A^k = [[a^k,0],[g_k,b^k]], g_k=(a^k-b^k)/(a-b); then
// out[b, j*CL+tloc+1, o] += g_{tloc+1}*f0[o] + b^{tloc+1}*o0[o]  (float4 RMW).
__global__ __launch_bounds__(256)
void fixup_kernel(float* __restrict__ out, const float* __restrict__ ws) {
    const int blk = blockIdx.x;
    const int b = blk >> 4;           // TC = 16
    const int j = blk & 15;
    if (j == 0) return;

    __shared__ float f0s[O_], o0s[O_];
    const int tid = threadIdx.x;
    if (tid < O_) {
        const float* wp = ws + ((size_t)(b * O_ + tid) * TC) * 2;
        float f = 0.f, oacc = 0.f;
        for (int m = 0; m < j; ++m) {      // <= 15 terms
            const float k  = (float)((j - 1 - m) * CL);
            const float a  = exp2f(k * L2A);
            const float bb = exp2f(k * L2B);
            const float g  = (a - bb) * INV_AB;
            const float sf = wp[m * 2 + 0];
            const float so = wp[m * 2 + 1];
            f    = fmaf(a, sf, f);
            oacc = fmaf(g, sf, fmaf(bb, so, oacc));
        }
        f0s[tid] = f;
        o0s[tid] = oacc;
    }
    __syncthreads();

    float4* ob = (float4*)(out + ((size_t)b * TOUT + (size_t)j * CL + 1) * O_);
#pragma unroll
    for (int it = 0; it < 2; ++it) {              // 500 float4
        const int e4 = it * 256 + tid;
        if (e4 < CL * 4) {
            const int tloc = e4 >> 2, qo = 4 * (e4 & 3);
            const float k  = (float)(tloc + 1);
            const float a  = exp2f(k * L2A);
            const float bb = exp2f(k * L2B);
            const float g  = (a - bb) * INV_AB;
            float4 v = ob[e4];
            v.x = fmaf(g, f0s[qo + 0], fmaf(bb, o0s[qo + 0], v.x));
            v.y = fmaf(g, f0s[qo + 1], fmaf(bb, o0s[qo + 1], v.y));
            v.z = fmaf(g, f0s[qo + 2], fmaf(bb, o0s[qo + 2], v.z));
            v.w = fmaf(g, f0s[qo + 3], fmaf(bb, o0s[qo + 3], v.w));
            ob[e4] = v;
        }
    }
}

extern "C" void kernel_launch(void* const* d_in, const int* in_sizes, int n_in,
                              void* d_out, int out_size, void* d_ws, size_t ws_size,
                              hipStream_t stream) {
    const float* in = (const float*)d_in[0];   // [B, T, H]
    const float* W  = (const float*)d_in[1];   // [H, O]
    float* out = (float*)d_out;                // [B, T+1, O]
    float* ws  = (float*)d_ws;                 // 128*16*16*2*4 B = 256 KiB

    h2scan_kernel<<<dim3(B_ * TC), dim3(256), 0, stream>>>(in, W, out, ws);
    fixup_kernel<<<dim3(B_ * TC), dim3(256), 0, stream>>>(out, ws);
}

// Round 13
// 68.415 us; speedup vs baseline: 1.2201x; 1.2201x over previous
//
#include <hip/hip_runtime.h>

// SpikingReadoutLayer (two-kernel; barrier-free counted-vmcnt main loop):
//   h2[b,t,o] = sum_h in[b,t,h] * W[h,o]
//   flt' = a*flt + h_t ; out' = b*out + flt (OLD flt); out_rec[b,0,:]=0
//
// Kernel 1: one block per (b, t-chunk of 250 rows), 4 waves. WAVE-OWNED
// staging (wave w stages exactly its own 64 rows via global_load_lds 16B DMA)
// -> chunk dependency is wave-local, NO __syncthreads in the 16-chunk loop.
// Per wave, per chunk: s_waitcnt vmcnt(4) (chunk c landed, c+1 in flight) ->
// ds_read own row -> s_waitcnt lgkmcnt(0) + sched_barrier (READ COMPLETE
// before overwrite DMA issues -- the R12 race fix) -> issue chunk c+2 into
// the freed buffer -> 256 FMAs (DMAs fly under them). XOR swizzle in the
// GLOBAL source quad (q^(r&3)), same XOR on read (both-sides rule).
// Then 3 barriers: scan tile, 16 serial chains (PAD=20), writeback; states->ws.
// Kernel 2: closed-form affine fixup (A^k analytic), float4 RMW (verified).

constexpr int B_ = 128, T_ = 2000, H_ = 256, O_ = 16;
constexpr int TOUT = T_ + 1;                 // 2001
constexpr int TC = 8, CL = 250;              // t-chunks per batch
constexpr int NHC = 16, HC = 16;             // h-chunks of 16 (64 B/row)
constexpr int PAD = 20;                      // scan tile row stride (floats)
constexpr float ALPHA = 0.95f, BETA = 0.9f;
constexpr float INV_AB = 20.0f;              // 1/(ALPHA-BETA)
constexpr float L2A = -0.07400058144377693f; // log2(0.95)
constexpr float L2B = -0.15200309344504997f; // log2(0.90)

#define AS1 __attribute__((address_space(1)))
#define AS3 __attribute__((address_space(3)))

__device__ __forceinline__ void gload16(const float* g, float* l) {
    __builtin_amdgcn_global_load_lds((const AS1 void*)g, (AS3 void*)l, 16, 0, 0);
}

__global__ __launch_bounds__(256, 4)
void h2scan_kernel(const float* __restrict__ in, const float* __restrict__ W,
                   float* __restrict__ out, float* __restrict__ ws) {
    __shared__ float lds[2 * 4096];    // 32 KB: two 16 KB buffers (1024 slots ea)
    const int tid  = threadIdx.x;
    const int w    = tid >> 6, lane = tid & 63;
    const int b    = blockIdx.x >> 3;  // TC = 8
    const int j    = blockIdx.x & 7;

    const float* inb = in + ((size_t)b * T_ + (size_t)j * CL) * H_;
    const int thrSlot = w * 256 + lane * 4;   // this thread's 4 slots per buffer
    const int rsw = lane & 3;

    float acc[16];
#pragma unroll
    for (int o = 0; o < 16; ++o) acc[o] = 0.f;

    // Wave w stages its own 64 rows [64w, 64w+64) for chunk c into buffer k.
    // Slot s = it*64+lane -> row r = 64w + s/4, quad q = s&3; source holds
    // global quad q^(r&3) (swizzle in SOURCE; LDS dest linear: uniform base +
    // lane*16 as HW requires). Rows >= CL clamp (written, never used).
    auto stage = [&](int c, int k) {
#pragma unroll
        for (int it = 0; it < 4; ++it) {
            const int s = it * 64 + lane;
            int r = w * 64 + (s >> 2);
            if (r > CL - 1) r = CL - 1;
            const int q = s & 3;
            gload16(inb + (size_t)r * H_ + c * HC + 4 * (q ^ (r & 3)),
                    &lds[(size_t)k * 4096 + (size_t)(w * 256 + s) * 4]);
        }
    };

    // prologue: 2-deep pipeline (8 DMA loads outstanding per wave)
    stage(0, 0);
    stage(1, 1);

    for (int c = 0; c < NHC - 1; ++c) {
        // chunk c's 4 loads landed; chunk c+1's 4 still in flight
        asm volatile("s_waitcnt vmcnt(4)" ::: "memory");
        __builtin_amdgcn_sched_barrier(0);
        const int k = c & 1;
        float4 xv[4];
#pragma unroll
        for (int p = 0; p < 4; ++p)
            xv[p] = *(const float4*)&lds[(size_t)k * 4096 +
                                         (size_t)(thrSlot + (p ^ rsw)) * 4];
        // RACE FIX: reads must COMPLETE (data in VGPRs) before the
        // overwriting DMA for chunk c+2 is issued into this buffer.
        asm volatile("s_waitcnt lgkmcnt(0)" ::: "memory");
        __builtin_amdgcn_sched_barrier(0);
        if (c < NHC - 2) stage(c + 2, k);    // refill the buffer just read

        const float* __restrict__ Wc = W + c * HC * O_;  // wave-uniform
#pragma unroll
        for (int p = 0; p < 4; ++p) {
            const float xe[4] = {xv[p].x, xv[p].y, xv[p].z, xv[p].w};
#pragma unroll
            for (int e = 0; e < 4; ++e) {
                const float x = xe[e];
                const float* wrow = Wc + (4 * p + e) * 16;
#pragma unroll
                for (int o = 0; o < 16; ++o)
                    acc[o] = fmaf(x, wrow[o], acc[o]);
            }
        }
    }
    {   // final chunk: drain all
        asm volatile("s_waitcnt vmcnt(0)" ::: "memory");
        __builtin_amdgcn_sched_barrier(0);
        const int c = NHC - 1, k = c & 1;
        float4 xv[4];
#pragma unroll
        for (int p = 0; p < 4; ++p)
            xv[p] = *(const float4*)&lds[(size_t)k * 4096 +
                                         (size_t)(thrSlot + (p ^ rsw)) * 4];
        const float* __restrict__ Wc = W + c * HC * O_;
#pragma unroll
        for (int p = 0; p < 4; ++p) {
            const float xe[4] = {xv[p].x, xv[p].y, xv[p].z, xv[p].w};
#pragma unroll
            for (int e = 0; e < 4; ++e) {
                const float x = xe[e];
                const float* wrow = Wc + (4 * p + e) * 16;
#pragma unroll
                for (int o = 0; o < 16; ++o)
                    acc[o] = fmaf(x, wrow[o], acc[o]);
            }
        }
    }
    __syncthreads();   // all waves done with buffers; tile overlays them

    // ---- acc -> scan tile ----
    if (tid < CL) {
        float4* tp = (float4*)&lds[tid * PAD];
        tp[0] = make_float4(acc[0],  acc[1],  acc[2],  acc[3]);
        tp[1] = make_float4(acc[4],  acc[5],  acc[6],  acc[7]);
        tp[2] = make_float4(acc[8],  acc[9],  acc[10], acc[11]);
        tp[3] = make_float4(acc[12], acc[13], acc[14], acc[15]);
    }
    __syncthreads();

    // ---- 16 serial chains down the columns (conflict-free, PAD=20) ----
    if (tid < O_) {
        float flt = 0.f, oo = 0.f;
        float* col = &lds[tid];
#pragma unroll 5
        for (int t = 0; t < CL; ++t) {
            const float h = col[t * PAD];
            const float no = fmaf(BETA, oo, flt);  // uses OLD flt
            flt = fmaf(ALPHA, flt, h);
            col[t * PAD] = no;
            oo = no;
        }
        float* wp = ws + ((size_t)(b * O_ + tid) * TC + j) * 2;
        wp[0] = flt;
        wp[1] = oo;
        if (j == 0) out[(size_t)b * TOUT * O_ + tid] = 0.f;  // out_rec[b,0,o]
    }
    __syncthreads();

    // ---- coalesced float4 writeback of LOCAL outputs ----
    float4* ob = (float4*)(out + ((size_t)b * TOUT + (size_t)j * CL + 1) * O_);
#pragma unroll
    for (int it = 0; it < 4; ++it) {              // CL*O_/4 = 1000 float4
        const int e4 = it * 256 + tid;
        if (e4 < CL * 4) {
            const int tloc = e4 >> 2, qo = 4 * (e4 & 3);
            const float* tp = &lds[tloc * PAD + qo];
            ob[e4] = make_float4(tp[0], tp[1], tp[2], tp[3]);
        }
    }
}

// Kernel 2: chunk j>0 start state s0 = sum_{m<j} A^{CL*(j-1-m)} * sigma_m,
// A^k = [[a^k,0],[g_k,b^k]], g_k=(a^k-b^k)/(a-b); then
// out[b, j*CL+tloc+1, o] += g_{tloc+1}*f0[o] + b^{tloc+1}*o0[o]  (float4 RMW).
__global__ __launch_bounds__(256)
void fixup_kernel(float* __restrict__ out, const float* __restrict__ ws) {
    const int blk = blockIdx.x;
    const int b = blk >> 3;           // TC = 8
    const int j = blk & 7;
    if (j == 0) return;

    __shared__ float f0s[O_], o0s[O_];
    const int tid = threadIdx.x;
    if (tid < O_) {
        const float* wp = ws + ((size_t)(b * O_ + tid) * TC) * 2;
        float f = 0.f, oacc = 0.f;
        for (int m = 0; m < j; ++m) {      // <= 7 terms
            const float k  = (float)((j - 1 - m) * CL);
            const float a  = exp2f(k * L2A);
            const float bb = exp2f(k * L2B);
            const float g  = (a - bb) * INV_AB;
            const float sf = wp[m * 2 + 0];
            const float so = wp[m * 2 + 1];
            f    = fmaf(a, sf, f);
            oacc = fmaf(g, sf, fmaf(bb, so, oacc));
        }
        f0s[tid] = f;
        o0s[tid] = oacc;
    }
    __syncthreads();

    float4* ob = (float4*)(out + ((size_t)b * TOUT + (size_t)j * CL + 1) * O_);
#pragma unroll
    for (int it = 0; it < 4; ++it) {              // 1000 float4
        const int e4 = it * 256 + tid;
        if (e4 < CL * 4) {
            const int tloc = e4 >> 2, qo = 4 * (e4 & 3);
            const float k  = (float)(tloc + 1);
            const float a  = exp2f(k * L2A);
            const float bb = exp2f(k * L2B);
            const float g  = (a - bb) * INV_AB;
            float4 v = ob[e4];
            v.x = fmaf(g, f0s[qo + 0], fmaf(bb, o0s[qo + 0], v.x));
            v.y = fmaf(g, f0s[qo + 1], fmaf(bb, o0s[qo + 1], v.y));
            v.z = fmaf(g, f0s[qo + 2], fmaf(bb, o0s[qo + 2], v.z));
            v.w = fmaf(g, f0s[qo + 3], fmaf(bb, o0s[qo + 3], v.w));
            ob[e4] = v;
        }
    }
}

extern "C" void kernel_launch(void* const* d_in, const int* in_sizes, int n_in,
                              void* d_out, int out_size, void* d_ws, size_t ws_size,
                              hipStream_t stream) {
    const float* in = (const float*)d_in[0];   // [B, T, H]
    const float* W  = (const float*)d_in[1];   // [H, O]
    float* out = (float*)d_out;                // [B, T+1, O]
    float* ws  = (float*)d_ws;                 // 128*16*8*2*4 B = 128 KiB

    h2scan_kernel<<<dim3(B_ * TC), dim3(256), 0, stream>>>(in, W, out, ws);
    fixup_kernel<<<dim3(B_ * TC), dim3(256), 0, stream>>>(out, ws);
}